// Round 2
// baseline (2874.728 us; speedup 1.0000x reference)
//
#include <hip/hip_runtime.h>
#include <cstdint>
#include <cstddef>

#define BBATCH 32
#define TT 14
#define MM 2048
#define QD 768
#define NHEAD 12
#define HD 64
#define FFD 3072
#define KVD 1024

typedef short bf16x8 __attribute__((ext_vector_type(8)));
typedef float f32x4 __attribute__((ext_vector_type(4)));

__device__ __forceinline__ uint16_t f2b(float f) {
  union { float f; uint32_t u; } v; v.f = f;
  uint32_t r = v.u + 0x7fffu + ((v.u >> 16) & 1u);
  return (uint16_t)(r >> 16);
}
__device__ __forceinline__ float b2f(uint16_t b) {
  union { uint32_t u; float f; } v; v.u = ((uint32_t)b) << 16; return v.f;
}

__device__ __forceinline__ void glds16(const void* g, void* l) {
  __builtin_amdgcn_global_load_lds(
      (const __attribute__((address_space(1))) void*)g,
      (__attribute__((address_space(3))) void*)l, 16, 0, 0);
}

// ---------------- cast f32 -> bf16, 8 elems/thread ----------------
__global__ void k_cast8(const float4* __restrict__ in, uint4* __restrict__ out) {
  int i = blockIdx.x * blockDim.x + threadIdx.x;
  float4 a = in[2 * i], b = in[2 * i + 1];
  uint4 o;
  o.x = (uint32_t)f2b(a.x) | ((uint32_t)f2b(a.y) << 16);
  o.y = (uint32_t)f2b(a.z) | ((uint32_t)f2b(a.w) << 16);
  o.z = (uint32_t)f2b(b.x) | ((uint32_t)f2b(b.y) << 16);
  o.w = (uint32_t)f2b(b.z) | ((uint32_t)f2b(b.w) << 16);
  out[i] = o;
}

// ------------- transpose-convert: in f32 [bz][R][C] -> out bf16 [bz][C][R] -------------
__global__ void k_transpose_bf16(const float* __restrict__ in, uint16_t* __restrict__ out,
                                 int R, int C) {
  __shared__ float tile[32][33];
  int bz = blockIdx.z;
  int c0 = blockIdx.x * 32, r0 = blockIdx.y * 32;
  int tx = threadIdx.x & 31, ty = threadIdx.x >> 5;  // 32 x 8
  const float* inb = in + (size_t)bz * R * C;
  uint16_t* outb = out + (size_t)bz * R * C;
#pragma unroll
  for (int rr = 0; rr < 32; rr += 8)
    tile[ty + rr][tx] = inb[(size_t)(r0 + ty + rr) * C + c0 + tx];
  __syncthreads();
#pragma unroll
  for (int rr = 0; rr < 32; rr += 8)
    outb[(size_t)(c0 + ty + rr) * R + r0 + tx] = f2b(tile[tx][ty + rr]);
}

__global__ void k_bias_concat(const float* __restrict__ bK, const float* __restrict__ bV,
                              float* __restrict__ out) {
  int i = blockIdx.x * 256 + threadIdx.x;  // 1536
  out[i] = (i < QD) ? bK[i] : bV[i - QD];
}

// ---------------- 128x128 bf16 MFMA GEMM: C = A @ Bt^T + bias, bf16 out ----------------
// A [M][K] bf16, Bt [N][K] bf16, C [M][N] bf16. M%128==0, N%128==0, K%32==0.
__global__ __launch_bounds__(256) void k_gemm128(
    const uint16_t* __restrict__ A, const uint16_t* __restrict__ Bt,
    const float* __restrict__ bias, uint16_t* __restrict__ C, int K, int N) {
  __shared__ __align__(16) uint16_t As[128 * 32];
  __shared__ __align__(16) uint16_t Bs[128 * 32];
  int tid = threadIdx.x;
  int w = tid >> 6, l = tid & 63;
  int m0 = blockIdx.y * 128, n0 = blockIdx.x * 128;
  int wm = (w >> 1) * 64, wn = (w & 1) * 64;

  f32x4 zero4 = {0.f, 0.f, 0.f, 0.f};
  f32x4 acc[4][4];
#pragma unroll
  for (int i = 0; i < 4; i++)
#pragma unroll
    for (int j = 0; j < 4; j++) acc[i][j] = zero4;

  int sr = tid >> 2;          // 0..63
  int sc = (tid & 3) * 8;     // k elem offset
  const uint16_t* gA0 = A + (size_t)(m0 + sr) * K + sc;
  const uint16_t* gA1 = A + (size_t)(m0 + 64 + sr) * K + sc;
  const uint16_t* gB0 = Bt + (size_t)(n0 + sr) * K + sc;
  const uint16_t* gB1 = Bt + (size_t)(n0 + 64 + sr) * K + sc;

  int lm = l & 15, q = l >> 4;
  for (int kt = 0; kt < K; kt += 32) {
    __syncthreads();
    glds16(gA0 + kt, As + w * 512);
    glds16(gA1 + kt, As + 2048 + w * 512);
    glds16(gB0 + kt, Bs + w * 512);
    glds16(gB1 + kt, Bs + 2048 + w * 512);
    __syncthreads();
    bf16x8 af[4], bfv[4];
#pragma unroll
    for (int i = 0; i < 4; i++) {
      af[i] = *(const bf16x8*)&As[(wm + i * 16 + lm) * 32 + q * 8];
      bfv[i] = *(const bf16x8*)&Bs[(wn + i * 16 + lm) * 32 + q * 8];
    }
#pragma unroll
    for (int i = 0; i < 4; i++)
#pragma unroll
      for (int j = 0; j < 4; j++)
        acc[i][j] = __builtin_amdgcn_mfma_f32_16x16x32_bf16(af[i], bfv[j], acc[i][j], 0, 0, 0);
  }
#pragma unroll
  for (int j = 0; j < 4; j++) {
    int col = n0 + wn + j * 16 + lm;
    float bc = bias[col];
#pragma unroll
    for (int i = 0; i < 4; i++) {
      int rowb = m0 + wm + i * 16 + q * 4;
#pragma unroll
      for (int r = 0; r < 4; r++) {
        float v = acc[i][j][r] + bc;
        C[(size_t)(rowb + r) * N + col] = f2b(v);
      }
    }
  }
}

// ---------------- 64x64 bf16 MFMA GEMM for FFN ----------------
template <bool RELU, bool OUTF32>
__global__ __launch_bounds__(256) void k_gemm64(
    const uint16_t* __restrict__ A, const uint16_t* __restrict__ Bt,
    const float* __restrict__ bias, void* __restrict__ Cv, int K, int N) {
  __shared__ __align__(16) uint16_t As[64 * 32];
  __shared__ __align__(16) uint16_t Bs[64 * 32];
  int tid = threadIdx.x;
  int w = tid >> 6, l = tid & 63;
  int m0 = blockIdx.y * 64, n0 = blockIdx.x * 64;
  int wm = (w >> 1) * 32, wn = (w & 1) * 32;
  f32x4 zero4 = {0.f, 0.f, 0.f, 0.f};
  f32x4 acc[2][2];
#pragma unroll
  for (int i = 0; i < 2; i++)
#pragma unroll
    for (int j = 0; j < 2; j++) acc[i][j] = zero4;

  int sr = tid >> 2, sc = (tid & 3) * 8;
  const uint16_t* gA = A + (size_t)(m0 + sr) * K + sc;
  const uint16_t* gB = Bt + (size_t)(n0 + sr) * K + sc;
  int lm = l & 15, q = l >> 4;
  for (int kt = 0; kt < K; kt += 32) {
    __syncthreads();
    glds16(gA + kt, As + w * 512);
    glds16(gB + kt, Bs + w * 512);
    __syncthreads();
    bf16x8 af[2], bfv[2];
#pragma unroll
    for (int i = 0; i < 2; i++) {
      af[i] = *(const bf16x8*)&As[(wm + i * 16 + lm) * 32 + q * 8];
      bfv[i] = *(const bf16x8*)&Bs[(wn + i * 16 + lm) * 32 + q * 8];
    }
#pragma unroll
    for (int i = 0; i < 2; i++)
#pragma unroll
      for (int j = 0; j < 2; j++)
        acc[i][j] = __builtin_amdgcn_mfma_f32_16x16x32_bf16(af[i], bfv[j], acc[i][j], 0, 0, 0);
  }
#pragma unroll
  for (int j = 0; j < 2; j++) {
    int col = n0 + wn + j * 16 + lm;
    float bc = bias[col];
#pragma unroll
    for (int i = 0; i < 2; i++) {
      int rowb = m0 + wm + i * 16 + q * 4;
#pragma unroll
      for (int r = 0; r < 4; r++) {
        float v = acc[i][j][r] + bc;
        if (RELU) v = fmaxf(v, 0.f);
        if (OUTF32)
          ((float*)Cv)[(size_t)(rowb + r) * N + col] = v;
        else
          ((uint16_t*)Cv)[(size_t)(rowb + r) * N + col] = f2b(v);
      }
    }
  }
}

// ---------------- grouped Q projection: per t, C[b][n] = X[b,t,:] @ WQt[t][n][:] + bQ ----
__global__ __launch_bounds__(256) void k_gemm_q(
    const uint16_t* __restrict__ Xb,   // [448][768] bf16 rows (b*14+t)
    const uint16_t* __restrict__ WQt,  // [14][768][768] bf16 (n-major)
    const float* __restrict__ bQ,      // [14][768]
    float* __restrict__ Q) {           // [448][768] f32
  __shared__ __align__(16) uint16_t As[32 * 32];
  __shared__ __align__(16) uint16_t Bs[64 * 32];
  int tid = threadIdx.x;
  int w = tid >> 6, l = tid & 63;
  int t = blockIdx.y, n0 = blockIdx.x * 64;
  const uint16_t* Wt = WQt + (size_t)t * QD * QD;
  f32x4 zero4 = {0.f, 0.f, 0.f, 0.f};
  f32x4 acc[2] = {zero4, zero4};
  int sr = tid >> 2, sc = (tid & 3) * 8;
  const uint16_t* gA = Xb + ((size_t)(sr * TT + t)) * QD + sc;  // valid for tid<128
  const uint16_t* gB = Wt + (size_t)(n0 + sr) * QD + sc;
  int lm = l & 15, q = l >> 4;
  for (int kt = 0; kt < QD; kt += 32) {
    __syncthreads();
    if (tid < 128) glds16(gA + kt, As + w * 512);
    glds16(gB + kt, Bs + w * 512);
    __syncthreads();
    bf16x8 bfv = *(const bf16x8*)&Bs[(w * 16 + lm) * 32 + q * 8];
#pragma unroll
    for (int i = 0; i < 2; i++) {
      bf16x8 af = *(const bf16x8*)&As[(i * 16 + lm) * 32 + q * 8];
      acc[i] = __builtin_amdgcn_mfma_f32_16x16x32_bf16(af, bfv, acc[i], 0, 0, 0);
    }
  }
  int col = n0 + w * 16 + lm;
  float bc = bQ[t * QD + col];
#pragma unroll
  for (int i = 0; i < 2; i++) {
    int b0 = i * 16 + q * 4;
#pragma unroll
    for (int r = 0; r < 4; r++) {
      int b = b0 + r;
      Q[((size_t)(b * TT + t)) * QD + col] = acc[i][r] + bc;
    }
  }
}

// ---------------- scores + softmax -> attn_w ----------------
// grid (tg=2, h=12, b=32), block 256. Each block: 7 t's, all 2048 m.
__global__ __launch_bounds__(256) void k_scores(
    const float* __restrict__ Q,       // [448][768]
    const uint16_t* __restrict__ CKV,  // [65536][1536], K at cols 0..767
    float* __restrict__ AW) {          // [B][T][H][M]
  __shared__ __align__(16) float Qs[7][64];
  __shared__ float redv[4];
  int tid = threadIdx.x;
  int tg = blockIdx.x, h = blockIdx.y, b = blockIdx.z;
  int t0 = tg * 7;
  // NOTE: block has 256 threads but 448 Q values — must loop (round-1 bug: t=4..6 never loaded)
  for (int i = tid; i < 7 * 64; i += 256) {
    int t = i >> 6, d = i & 63;
    Qs[t][d] = Q[((size_t)(b * TT + t0 + t)) * QD + h * HD + d] * 0.125f;
  }
  __syncthreads();
  float acc[7][8];
#pragma unroll
  for (int t = 0; t < 7; t++)
#pragma unroll
    for (int c = 0; c < 8; c++) acc[t][c] = 0.f;

  const uint16_t* kbase = CKV + ((size_t)b * MM) * 1536 + h * HD;
  for (int dv = 0; dv < 8; dv++) {
    float qv[7][8];
#pragma unroll
    for (int t = 0; t < 7; t++) {
      float4 qa = *(const float4*)&Qs[t][dv * 8];
      float4 qb = *(const float4*)&Qs[t][dv * 8 + 4];
      qv[t][0] = qa.x; qv[t][1] = qa.y; qv[t][2] = qa.z; qv[t][3] = qa.w;
      qv[t][4] = qb.x; qv[t][5] = qb.y; qv[t][6] = qb.z; qv[t][7] = qb.w;
    }
#pragma unroll
    for (int c = 0; c < 8; c++) {
      int m = c * 256 + tid;
      uint4 u = *(const uint4*)(kbase + (size_t)m * 1536 + dv * 8);
      float kf[8];
      kf[0] = __uint_as_float(u.x << 16); kf[1] = __uint_as_float(u.x & 0xffff0000u);
      kf[2] = __uint_as_float(u.y << 16); kf[3] = __uint_as_float(u.y & 0xffff0000u);
      kf[4] = __uint_as_float(u.z << 16); kf[5] = __uint_as_float(u.z & 0xffff0000u);
      kf[6] = __uint_as_float(u.w << 16); kf[7] = __uint_as_float(u.w & 0xffff0000u);
#pragma unroll
      for (int t = 0; t < 7; t++)
#pragma unroll
        for (int j = 0; j < 8; j++) acc[t][c] += kf[j] * qv[t][j];
    }
  }
  // softmax per t over 2048 (8 regs x 256 threads)
  int lane = tid & 63, w = tid >> 6;
#pragma unroll
  for (int t = 0; t < 7; t++) {
    float mx = acc[t][0];
#pragma unroll
    for (int c = 1; c < 8; c++) mx = fmaxf(mx, acc[t][c]);
#pragma unroll
    for (int o = 32; o > 0; o >>= 1) mx = fmaxf(mx, __shfl_xor(mx, o));
    if (lane == 0) redv[w] = mx;
    __syncthreads();
    mx = fmaxf(fmaxf(redv[0], redv[1]), fmaxf(redv[2], redv[3]));
    __syncthreads();
    float s = 0.f;
#pragma unroll
    for (int c = 0; c < 8; c++) {
      float e = __expf(acc[t][c] - mx);
      acc[t][c] = e;
      s += e;
    }
#pragma unroll
    for (int o = 32; o > 0; o >>= 1) s += __shfl_xor(s, o);
    if (lane == 0) redv[w] = s;
    __syncthreads();
    s = redv[0] + redv[1] + redv[2] + redv[3];
    __syncthreads();
    float inv = 1.f / s;
    size_t rowb = ((size_t)((b * TT + t0 + t) * NHEAD + h)) * MM;
#pragma unroll
    for (int c = 0; c < 8; c++) AW[rowb + c * 256 + tid] = acc[t][c] * inv;
  }
}

// ---------------- attn_out = attn_w @ V ----------------
// grid (h=12, b=32), block 256: thread = (d = tid&63, tg = tid>>6), t = tg+4i
__global__ __launch_bounds__(256) void k_attnout(
    const float* __restrict__ AW, const uint16_t* __restrict__ CKV,
    float* __restrict__ AO) {  // [448][768]
  int tid = threadIdx.x;
  int h = blockIdx.x, b = blockIdx.y;
  int d = tid & 63, tg = tid >> 6;
  float acc[4] = {0.f, 0.f, 0.f, 0.f};
  const uint16_t* vbase = CKV + ((size_t)b * MM) * 1536 + QD + h * HD + d;
  const float* pbase = AW + ((size_t)(b * TT * NHEAD + h)) * MM;
#pragma unroll 4
  for (int m = 0; m < MM; m++) {
    float v = b2f(vbase[(size_t)m * 1536]);
#pragma unroll
    for (int i = 0; i < 4; i++) {
      int t = tg + i * 4;
      if (t < TT) acc[i] += pbase[(size_t)t * NHEAD * MM + m] * v;
    }
  }
#pragma unroll
  for (int i = 0; i < 4; i++) {
    int t = tg + i * 4;
    if (t < TT) AO[((size_t)(b * TT + t)) * QD + h * HD + d] = acc[i];
  }
}

// ---------------- add + layernorm ----------------
__global__ __launch_bounds__(256) void k_add_ln(
    const float* __restrict__ X, const float* __restrict__ Y,
    const float* __restrict__ g, const float* __restrict__ be,
    float* __restrict__ outF, uint16_t* __restrict__ outB) {
  __shared__ float redS[4], redQ[4];
  int r = blockIdx.x, tid = threadIdx.x;
  size_t base = (size_t)r * QD;
  float e[3];
  float s = 0.f, sq = 0.f;
#pragma unroll
  for (int j = 0; j < 3; j++) {
    float v = X[base + tid + j * 256] + Y[base + tid + j * 256];
    e[j] = v; s += v; sq += v * v;
  }
#pragma unroll
  for (int o = 32; o > 0; o >>= 1) { s += __shfl_xor(s, o); sq += __shfl_xor(sq, o); }
  if ((tid & 63) == 0) { redS[tid >> 6] = s; redQ[tid >> 6] = sq; }
  __syncthreads();
  s = redS[0] + redS[1] + redS[2] + redS[3];
  sq = redQ[0] + redQ[1] + redQ[2] + redQ[3];
  float mu = s * (1.f / QD);
  float var = sq * (1.f / QD) - mu * mu;
  float rstd = rsqrtf(var + 1e-5f);
#pragma unroll
  for (int j = 0; j < 3; j++) {
    int i = tid + j * 256;
    float v = (e[j] - mu) * rstd * g[i] + be[i];
    outF[base + i] = v;
    if (outB) outB[base + i] = f2b(v);
  }
}

extern "C" void kernel_launch(void* const* d_in, const int* in_sizes, int n_in,
                              void* d_out, int out_size, void* d_ws, size_t ws_size,
                              hipStream_t stream) {
  const float* tok = (const float*)d_in[0];   // [32][14][768]
  const float* kve = (const float*)d_in[1];   // [32][2048][1024]
  const float* WQ  = (const float*)d_in[2];   // [14][768][768]
  const float* bQ  = (const float*)d_in[3];   // [14][768]
  const float* WK  = (const float*)d_in[4];   // [1024][768]
  const float* bK  = (const float*)d_in[5];
  const float* WV  = (const float*)d_in[6];
  const float* bV  = (const float*)d_in[7];
  const float* W1  = (const float*)d_in[8];   // [768][3072]
  const float* b1  = (const float*)d_in[9];
  const float* W2  = (const float*)d_in[10];  // [3072][768]
  const float* b2  = (const float*)d_in[11];
  const float* g1  = (const float*)d_in[12];
  const float* be1 = (const float*)d_in[13];
  const float* g2  = (const float*)d_in[14];
  const float* be2 = (const float*)d_in[15];

  float* outp = (float*)d_out;            // [448][768]
  float* AW = outp + 448 * 768;           // [32][14][12][2048]

  char* p = (char*)d_ws;
  auto nxt = [&](size_t bytes) -> char* {
    char* r = p;
    p += (bytes + 255) & ~(size_t)255;
    return r;
  };
  uint16_t* Abf   = (uint16_t*)nxt((size_t)67108864 * 2);   // KV embeddings bf16
  uint16_t* CKV   = (uint16_t*)nxt((size_t)100663296 * 2);  // [65536][1536] K|V bf16
  uint16_t* Wkvt  = (uint16_t*)nxt((size_t)1572864 * 2);    // [1536][1024]
  uint16_t* WQt   = (uint16_t*)nxt((size_t)8257536 * 2);    // [14][768][768]
  uint16_t* W1t   = (uint16_t*)nxt((size_t)2359296 * 2);    // [3072][768]
  uint16_t* W2t   = (uint16_t*)nxt((size_t)2359296 * 2);    // [768][3072]
  uint16_t* xtokb = (uint16_t*)nxt((size_t)344064 * 2);     // tokens bf16
  float* biaskv   = (float*)nxt(1536 * 4);
  float* Qws      = (float*)nxt((size_t)344064 * 4);
  float* AOws     = (float*)nxt((size_t)344064 * 4);
  float* xws      = (float*)nxt((size_t)344064 * 4);
  uint16_t* xbf   = (uint16_t*)nxt((size_t)344064 * 2);
  uint16_t* h1bf  = (uint16_t*)nxt((size_t)1376256 * 2);    // [448][3072]
  float* yws      = (float*)nxt((size_t)344064 * 4);

  // conversions
  k_cast8<<<dim3(32768), dim3(256), 0, stream>>>((const float4*)kve, (uint4*)Abf);
  k_cast8<<<dim3(168), dim3(256), 0, stream>>>((const float4*)tok, (uint4*)xtokb);
  k_transpose_bf16<<<dim3(24, 32, 1), dim3(256), 0, stream>>>(WK, Wkvt, 1024, 768);
  k_transpose_bf16<<<dim3(24, 32, 1), dim3(256), 0, stream>>>(WV, Wkvt + (size_t)768 * 1024, 1024, 768);
  k_transpose_bf16<<<dim3(24, 24, 14), dim3(256), 0, stream>>>(WQ, WQt, 768, 768);
  k_transpose_bf16<<<dim3(96, 24, 1), dim3(256), 0, stream>>>(W1, W1t, 768, 3072);
  k_transpose_bf16<<<dim3(24, 96, 1), dim3(256), 0, stream>>>(W2, W2t, 3072, 768);
  k_bias_concat<<<dim3(6), dim3(256), 0, stream>>>(bK, bV, biaskv);

  // K|V projection: [65536][1024] @ -> [65536][1536]
  k_gemm128<<<dim3(12, 512), dim3(256), 0, stream>>>(Abf, Wkvt, biaskv, CKV, 1024, 1536);

  // Q projection (per-t grouped)
  k_gemm_q<<<dim3(12, 14), dim3(256), 0, stream>>>(xtokb, WQt, bQ, Qws);

  // scores + softmax -> attn_w (f32, second output)
  k_scores<<<dim3(2, 12, 32), dim3(256), 0, stream>>>(Qws, CKV, AW);

  // attn_out = attn_w @ V
  k_attnout<<<dim3(12, 32), dim3(256), 0, stream>>>(AW, CKV, AOws);

  // x = LN(tok + attn_out)
  k_add_ln<<<dim3(448), dim3(256), 0, stream>>>(tok, AOws, g1, be1, xws, xbf);

  // FFN
  k_gemm64<true, false><<<dim3(48, 7), dim3(256), 0, stream>>>(xbf, W1t, b1, (void*)h1bf, 768, 3072);
  k_gemm64<false, true><<<dim3(12, 7), dim3(256), 0, stream>>>(h1bf, W2t, b2, (void*)yws, 3072, 768);

  // out = LN(x + ff)
  k_add_ln<<<dim3(448), dim3(256), 0, stream>>>(xws, yws, g2, be2, outp, (uint16_t*)nullptr);
}

// Round 3
// 1412.984 us; speedup vs baseline: 2.0345x; 2.0345x over previous
//
#include <hip/hip_runtime.h>
#include <cstdint>
#include <cstddef>

#define BBATCH 32
#define TT 14
#define MM 2048
#define QD 768
#define NHEAD 12
#define HD 64
#define FFD 3072
#define KVD 1024

typedef short bf16x8 __attribute__((ext_vector_type(8)));
typedef float f32x4 __attribute__((ext_vector_type(4)));

__device__ __forceinline__ uint16_t f2b(float f) {
  union { float f; uint32_t u; } v; v.f = f;
  uint32_t r = v.u + 0x7fffu + ((v.u >> 16) & 1u);
  return (uint16_t)(r >> 16);
}
__device__ __forceinline__ float b2f(uint16_t b) {
  union { uint32_t u; float f; } v; v.u = ((uint32_t)b) << 16; return v.f;
}

__device__ __forceinline__ void glds16(const void* g, void* l) {
  __builtin_amdgcn_global_load_lds(
      (const __attribute__((address_space(1))) void*)g,
      (__attribute__((address_space(3))) void*)l, 16, 0, 0);
}

// ---------------- cast f32 -> bf16, 8 elems/thread ----------------
__global__ void k_cast8(const float4* __restrict__ in, uint4* __restrict__ out) {
  int i = blockIdx.x * blockDim.x + threadIdx.x;
  float4 a = in[2 * i], b = in[2 * i + 1];
  uint4 o;
  o.x = (uint32_t)f2b(a.x) | ((uint32_t)f2b(a.y) << 16);
  o.y = (uint32_t)f2b(a.z) | ((uint32_t)f2b(a.w) << 16);
  o.z = (uint32_t)f2b(b.x) | ((uint32_t)f2b(b.y) << 16);
  o.w = (uint32_t)f2b(b.z) | ((uint32_t)f2b(b.w) << 16);
  out[i] = o;
}

// ------------- transpose-convert: in f32 [bz][R][C] -> out bf16 [bz][C][R] -------------
__global__ void k_transpose_bf16(const float* __restrict__ in, uint16_t* __restrict__ out,
                                 int R, int C) {
  __shared__ float tile[32][33];
  int bz = blockIdx.z;
  int c0 = blockIdx.x * 32, r0 = blockIdx.y * 32;
  int tx = threadIdx.x & 31, ty = threadIdx.x >> 5;  // 32 x 8
  const float* inb = in + (size_t)bz * R * C;
  uint16_t* outb = out + (size_t)bz * R * C;
#pragma unroll
  for (int rr = 0; rr < 32; rr += 8)
    tile[ty + rr][tx] = inb[(size_t)(r0 + ty + rr) * C + c0 + tx];
  __syncthreads();
#pragma unroll
  for (int rr = 0; rr < 32; rr += 8)
    outb[(size_t)(c0 + ty + rr) * R + r0 + tx] = f2b(tile[tx][ty + rr]);
}

__global__ void k_bias_concat(const float* __restrict__ bK, const float* __restrict__ bV,
                              float* __restrict__ out) {
  int i = blockIdx.x * 256 + threadIdx.x;  // 1536
  out[i] = (i < QD) ? bK[i] : bV[i - QD];
}

// ---------------- KV projection GEMM: 128x128 tiles, writes head-major K and transposed V ---
// A [65536][1024] bf16 (row = b*2048+m), Bt [1536][1024] bf16.
// K part (col<768):  Kh[b][h][m][64]   (h = col/64, d = col%64)
// V part (col>=768): Vt[b][h][d][2048] (h = (col-768)/64, d = (col-768)%64)
__global__ __launch_bounds__(256) void k_gemm_kv(
    const uint16_t* __restrict__ A, const uint16_t* __restrict__ Bt,
    const float* __restrict__ bias, uint16_t* __restrict__ Kh, uint16_t* __restrict__ Vt) {
  __shared__ __align__(16) uint16_t As[128 * 32];
  __shared__ __align__(16) uint16_t Bs[128 * 32];
  const int K = KVD;
  int tid = threadIdx.x;
  int w = tid >> 6, l = tid & 63;
  int m0 = blockIdx.y * 128, n0 = blockIdx.x * 128;
  int wm = (w >> 1) * 64, wn = (w & 1) * 64;

  f32x4 zero4 = {0.f, 0.f, 0.f, 0.f};
  f32x4 acc[4][4];
#pragma unroll
  for (int i = 0; i < 4; i++)
#pragma unroll
    for (int j = 0; j < 4; j++) acc[i][j] = zero4;

  int sr = tid >> 2;
  int sc = (tid & 3) * 8;
  const uint16_t* gA0 = A + (size_t)(m0 + sr) * K + sc;
  const uint16_t* gA1 = A + (size_t)(m0 + 64 + sr) * K + sc;
  const uint16_t* gB0 = Bt + (size_t)(n0 + sr) * K + sc;
  const uint16_t* gB1 = Bt + (size_t)(n0 + 64 + sr) * K + sc;

  int lm = l & 15, q = l >> 4;
  for (int kt = 0; kt < K; kt += 32) {
    __syncthreads();
    glds16(gA0 + kt, As + w * 512);
    glds16(gA1 + kt, As + 2048 + w * 512);
    glds16(gB0 + kt, Bs + w * 512);
    glds16(gB1 + kt, Bs + 2048 + w * 512);
    __syncthreads();
    bf16x8 af[4], bfv[4];
#pragma unroll
    for (int i = 0; i < 4; i++) {
      af[i] = *(const bf16x8*)&As[(wm + i * 16 + lm) * 32 + q * 8];
      bfv[i] = *(const bf16x8*)&Bs[(wn + i * 16 + lm) * 32 + q * 8];
    }
#pragma unroll
    for (int i = 0; i < 4; i++)
#pragma unroll
      for (int j = 0; j < 4; j++)
        acc[i][j] = __builtin_amdgcn_mfma_f32_16x16x32_bf16(af[i], bfv[j], acc[i][j], 0, 0, 0);
  }
#pragma unroll
  for (int j = 0; j < 4; j++) {
    int col = n0 + wn + j * 16 + lm;
    float bc = bias[col];
    bool isV = col >= QD;            // uniform across lanes (64-aligned boundary)
    int c2 = isV ? col - QD : col;
    int h = c2 >> 6, d = c2 & 63;
#pragma unroll
    for (int i = 0; i < 4; i++) {
      int rowb = m0 + wm + i * 16 + q * 4;
#pragma unroll
      for (int r = 0; r < 4; r++) {
        int row = rowb + r;
        int b = row >> 11, m = row & 2047;
        float v = acc[i][j][r] + bc;
        if (isV)
          Vt[((((size_t)b * NHEAD + h) * HD) + d) * MM + m] = f2b(v);
        else
          Kh[(((size_t)b * NHEAD + h) * MM + m) * HD + d] = f2b(v);
      }
    }
  }
}

// ---------------- 64x64 bf16 MFMA GEMM for FFN ----------------
template <bool RELU, bool OUTF32>
__global__ __launch_bounds__(256) void k_gemm64(
    const uint16_t* __restrict__ A, const uint16_t* __restrict__ Bt,
    const float* __restrict__ bias, void* __restrict__ Cv, int K, int N) {
  __shared__ __align__(16) uint16_t As[64 * 32];
  __shared__ __align__(16) uint16_t Bs[64 * 32];
  int tid = threadIdx.x;
  int w = tid >> 6, l = tid & 63;
  int m0 = blockIdx.y * 64, n0 = blockIdx.x * 64;
  int wm = (w >> 1) * 32, wn = (w & 1) * 32;
  f32x4 zero4 = {0.f, 0.f, 0.f, 0.f};
  f32x4 acc[2][2];
#pragma unroll
  for (int i = 0; i < 2; i++)
#pragma unroll
    for (int j = 0; j < 2; j++) acc[i][j] = zero4;

  int sr = tid >> 2, sc = (tid & 3) * 8;
  const uint16_t* gA = A + (size_t)(m0 + sr) * K + sc;
  const uint16_t* gB = Bt + (size_t)(n0 + sr) * K + sc;
  int lm = l & 15, q = l >> 4;
  for (int kt = 0; kt < K; kt += 32) {
    __syncthreads();
    glds16(gA + kt, As + w * 512);
    glds16(gB + kt, Bs + w * 512);
    __syncthreads();
    bf16x8 af[2], bfv[2];
#pragma unroll
    for (int i = 0; i < 2; i++) {
      af[i] = *(const bf16x8*)&As[(wm + i * 16 + lm) * 32 + q * 8];
      bfv[i] = *(const bf16x8*)&Bs[(wn + i * 16 + lm) * 32 + q * 8];
    }
#pragma unroll
    for (int i = 0; i < 2; i++)
#pragma unroll
      for (int j = 0; j < 2; j++)
        acc[i][j] = __builtin_amdgcn_mfma_f32_16x16x32_bf16(af[i], bfv[j], acc[i][j], 0, 0, 0);
  }
#pragma unroll
  for (int j = 0; j < 2; j++) {
    int col = n0 + wn + j * 16 + lm;
    float bc = bias[col];
#pragma unroll
    for (int i = 0; i < 2; i++) {
      int rowb = m0 + wm + i * 16 + q * 4;
#pragma unroll
      for (int r = 0; r < 4; r++) {
        float v = acc[i][j][r] + bc;
        if (RELU) v = fmaxf(v, 0.f);
        if (OUTF32)
          ((float*)Cv)[(size_t)(rowb + r) * N + col] = v;
        else
          ((uint16_t*)Cv)[(size_t)(rowb + r) * N + col] = f2b(v);
      }
    }
  }
}

// ---------------- grouped Q projection ----------------
__global__ __launch_bounds__(256) void k_gemm_q(
    const uint16_t* __restrict__ Xb, const uint16_t* __restrict__ WQt,
    const float* __restrict__ bQ, float* __restrict__ Q) {
  __shared__ __align__(16) uint16_t As[32 * 32];
  __shared__ __align__(16) uint16_t Bs[64 * 32];
  int tid = threadIdx.x;
  int w = tid >> 6, l = tid & 63;
  int t = blockIdx.y, n0 = blockIdx.x * 64;
  const uint16_t* Wt = WQt + (size_t)t * QD * QD;
  f32x4 zero4 = {0.f, 0.f, 0.f, 0.f};
  f32x4 acc[2] = {zero4, zero4};
  int sr = tid >> 2, sc = (tid & 3) * 8;
  const uint16_t* gA = Xb + ((size_t)(sr * TT + t)) * QD + sc;
  const uint16_t* gB = Wt + (size_t)(n0 + sr) * QD + sc;
  int lm = l & 15, q = l >> 4;
  for (int kt = 0; kt < QD; kt += 32) {
    __syncthreads();
    if (tid < 128) glds16(gA + kt, As + w * 512);
    glds16(gB + kt, Bs + w * 512);
    __syncthreads();
    bf16x8 bfv = *(const bf16x8*)&Bs[(w * 16 + lm) * 32 + q * 8];
#pragma unroll
    for (int i = 0; i < 2; i++) {
      bf16x8 af = *(const bf16x8*)&As[(i * 16 + lm) * 32 + q * 8];
      acc[i] = __builtin_amdgcn_mfma_f32_16x16x32_bf16(af, bfv, acc[i], 0, 0, 0);
    }
  }
  int col = n0 + w * 16 + lm;
  float bc = bQ[t * QD + col];
#pragma unroll
  for (int i = 0; i < 2; i++) {
    int b0 = i * 16 + q * 4;
#pragma unroll
    for (int r = 0; r < 4; r++) {
      int b = b0 + r;
      Q[((size_t)(b * TT + t)) * QD + col] = acc[i][r] + bc;
    }
  }
}

// ---------------- scores + softmax -> attn_w ----------------
// grid (tg=2, h=12, b=32), block 256. K rows consumed whole (L1-friendly).
__global__ __launch_bounds__(256) void k_scores(
    const float* __restrict__ Q,      // [448][768]
    const uint16_t* __restrict__ Kh,  // [b][h][m][64]
    float* __restrict__ AW) {         // [B][T][H][M]
  __shared__ __align__(16) float Qs[7][64];
  __shared__ float redv[4];
  int tid = threadIdx.x;
  int tg = blockIdx.x, h = blockIdx.y, b = blockIdx.z;
  int t0 = tg * 7;
  for (int i = tid; i < 7 * 64; i += 256) {
    int t = i >> 6, d = i & 63;
    Qs[t][d] = Q[((size_t)(b * TT + t0 + t)) * QD + h * HD + d] * 0.125f;
  }
  __syncthreads();
  float acc[7][8];
#pragma unroll
  for (int t = 0; t < 7; t++)
#pragma unroll
    for (int c = 0; c < 8; c++) acc[t][c] = 0.f;

  const uint16_t* kb = Kh + ((size_t)(b * NHEAD + h)) * MM * HD;
  for (int c = 0; c < 8; c++) {
    const uint16_t* kr = kb + (size_t)(c * 256 + tid) * HD;
#pragma unroll
    for (int dv = 0; dv < 8; dv++) {
      uint4 u = *(const uint4*)(kr + dv * 8);
      float kf[8];
      kf[0] = __uint_as_float(u.x << 16); kf[1] = __uint_as_float(u.x & 0xffff0000u);
      kf[2] = __uint_as_float(u.y << 16); kf[3] = __uint_as_float(u.y & 0xffff0000u);
      kf[4] = __uint_as_float(u.z << 16); kf[5] = __uint_as_float(u.z & 0xffff0000u);
      kf[6] = __uint_as_float(u.w << 16); kf[7] = __uint_as_float(u.w & 0xffff0000u);
#pragma unroll
      for (int t = 0; t < 7; t++) {
        float4 qa = *(const float4*)&Qs[t][dv * 8];
        float4 qb = *(const float4*)&Qs[t][dv * 8 + 4];
        float s = acc[t][c];
        s = fmaf(kf[0], qa.x, s); s = fmaf(kf[1], qa.y, s);
        s = fmaf(kf[2], qa.z, s); s = fmaf(kf[3], qa.w, s);
        s = fmaf(kf[4], qb.x, s); s = fmaf(kf[5], qb.y, s);
        s = fmaf(kf[6], qb.z, s); s = fmaf(kf[7], qb.w, s);
        acc[t][c] = s;
      }
    }
  }
  // softmax per t over 2048
  int lane = tid & 63, w = tid >> 6;
#pragma unroll
  for (int t = 0; t < 7; t++) {
    float mx = acc[t][0];
#pragma unroll
    for (int c = 1; c < 8; c++) mx = fmaxf(mx, acc[t][c]);
#pragma unroll
    for (int o = 32; o > 0; o >>= 1) mx = fmaxf(mx, __shfl_xor(mx, o));
    if (lane == 0) redv[w] = mx;
    __syncthreads();
    mx = fmaxf(fmaxf(redv[0], redv[1]), fmaxf(redv[2], redv[3]));
    __syncthreads();
    float s = 0.f;
#pragma unroll
    for (int c = 0; c < 8; c++) {
      float e = __expf(acc[t][c] - mx);
      acc[t][c] = e;
      s += e;
    }
#pragma unroll
    for (int o = 32; o > 0; o >>= 1) s += __shfl_xor(s, o);
    if (lane == 0) redv[w] = s;
    __syncthreads();
    s = redv[0] + redv[1] + redv[2] + redv[3];
    __syncthreads();
    float inv = 1.f / s;
    size_t rowb = ((size_t)((b * TT + t0 + t) * NHEAD + h)) * MM;
#pragma unroll
    for (int c = 0; c < 8; c++) AW[rowb + c * 256 + tid] = acc[t][c] * inv;
  }
}

// ---------------- attn_out = attn_w @ V  (V pre-transposed per head) ----------------
// grid (12, 32), block 256. thread: d = tid&63 (own Vt row), wave tg -> t = tg*4+i.
__global__ __launch_bounds__(256) void k_attnout(
    const float* __restrict__ AW, const uint16_t* __restrict__ Vt,
    float* __restrict__ AO) {
  int tid = threadIdx.x;
  int h = blockIdx.x, b = blockIdx.y;
  int d = tid & 63, tg = tid >> 6;
  const uint16_t* vr = Vt + (((size_t)(b * NHEAD + h)) * HD + d) * MM;
  const float* pb = AW + ((size_t)(b * TT * NHEAD + h)) * MM;
  float acc[4] = {0.f, 0.f, 0.f, 0.f};
#pragma unroll 2
  for (int mc = 0; mc < MM; mc += 8) {
    uint4 u = *(const uint4*)(vr + mc);
    float vf[8];
    vf[0] = __uint_as_float(u.x << 16); vf[1] = __uint_as_float(u.x & 0xffff0000u);
    vf[2] = __uint_as_float(u.y << 16); vf[3] = __uint_as_float(u.y & 0xffff0000u);
    vf[4] = __uint_as_float(u.z << 16); vf[5] = __uint_as_float(u.z & 0xffff0000u);
    vf[6] = __uint_as_float(u.w << 16); vf[7] = __uint_as_float(u.w & 0xffff0000u);
#pragma unroll
    for (int i = 0; i < 4; i++) {
      int t = tg * 4 + i;
      if (t < TT) {
        const float* pr = pb + (size_t)t * NHEAD * MM + mc;
        float4 p0 = *(const float4*)pr;
        float4 p1 = *(const float4*)(pr + 4);
        float s = acc[i];
        s = fmaf(vf[0], p0.x, s); s = fmaf(vf[1], p0.y, s);
        s = fmaf(vf[2], p0.z, s); s = fmaf(vf[3], p0.w, s);
        s = fmaf(vf[4], p1.x, s); s = fmaf(vf[5], p1.y, s);
        s = fmaf(vf[6], p1.z, s); s = fmaf(vf[7], p1.w, s);
        acc[i] = s;
      }
    }
  }
#pragma unroll
  for (int i = 0; i < 4; i++) {
    int t = tg * 4 + i;
    if (t < TT) AO[((size_t)(b * TT + t)) * QD + h * HD + d] = acc[i];
  }
}

// ---------------- add + layernorm ----------------
__global__ __launch_bounds__(256) void k_add_ln(
    const float* __restrict__ X, const float* __restrict__ Y,
    const float* __restrict__ g, const float* __restrict__ be,
    float* __restrict__ outF, uint16_t* __restrict__ outB) {
  __shared__ float redS[4], redQ[4];
  int r = blockIdx.x, tid = threadIdx.x;
  size_t base = (size_t)r * QD;
  float e[3];
  float s = 0.f, sq = 0.f;
#pragma unroll
  for (int j = 0; j < 3; j++) {
    float v = X[base + tid + j * 256] + Y[base + tid + j * 256];
    e[j] = v; s += v; sq += v * v;
  }
#pragma unroll
  for (int o = 32; o > 0; o >>= 1) { s += __shfl_xor(s, o); sq += __shfl_xor(sq, o); }
  if ((tid & 63) == 0) { redS[tid >> 6] = s; redQ[tid >> 6] = sq; }
  __syncthreads();
  s = redS[0] + redS[1] + redS[2] + redS[3];
  sq = redQ[0] + redQ[1] + redQ[2] + redQ[3];
  float mu = s * (1.f / QD);
  float var = sq * (1.f / QD) - mu * mu;
  float rstd = rsqrtf(var + 1e-5f);
#pragma unroll
  for (int j = 0; j < 3; j++) {
    int i = tid + j * 256;
    float v = (e[j] - mu) * rstd * g[i] + be[i];
    outF[base + i] = v;
    if (outB) outB[base + i] = f2b(v);
  }
}

extern "C" void kernel_launch(void* const* d_in, const int* in_sizes, int n_in,
                              void* d_out, int out_size, void* d_ws, size_t ws_size,
                              hipStream_t stream) {
  const float* tok = (const float*)d_in[0];
  const float* kve = (const float*)d_in[1];
  const float* WQ  = (const float*)d_in[2];
  const float* bQ  = (const float*)d_in[3];
  const float* WK  = (const float*)d_in[4];
  const float* bK  = (const float*)d_in[5];
  const float* WV  = (const float*)d_in[6];
  const float* bV  = (const float*)d_in[7];
  const float* W1  = (const float*)d_in[8];
  const float* b1  = (const float*)d_in[9];
  const float* W2  = (const float*)d_in[10];
  const float* b2  = (const float*)d_in[11];
  const float* g1  = (const float*)d_in[12];
  const float* be1 = (const float*)d_in[13];
  const float* g2  = (const float*)d_in[14];
  const float* be2 = (const float*)d_in[15];

  float* outp = (float*)d_out;            // [448][768]
  float* AW = outp + 448 * 768;           // [32][14][12][2048]

  char* p = (char*)d_ws;
  auto nxt = [&](size_t bytes) -> char* {
    char* r = p;
    p += (bytes + 255) & ~(size_t)255;
    return r;
  };
  uint16_t* Abf   = (uint16_t*)nxt((size_t)67108864 * 2);   // KV embeddings bf16
  uint16_t* Kh    = (uint16_t*)nxt((size_t)50331648 * 2);   // [32][12][2048][64]
  uint16_t* Vt    = (uint16_t*)nxt((size_t)50331648 * 2);   // [32][12][64][2048]
  uint16_t* Wkvt  = (uint16_t*)nxt((size_t)1572864 * 2);    // [1536][1024]
  uint16_t* WQt   = (uint16_t*)nxt((size_t)8257536 * 2);    // [14][768][768]
  uint16_t* W1t   = (uint16_t*)nxt((size_t)2359296 * 2);    // [3072][768]
  uint16_t* W2t   = (uint16_t*)nxt((size_t)2359296 * 2);    // [768][3072]
  uint16_t* xtokb = (uint16_t*)nxt((size_t)344064 * 2);     // tokens bf16
  float* biaskv   = (float*)nxt(1536 * 4);
  float* Qws      = (float*)nxt((size_t)344064 * 4);
  float* AOws     = (float*)nxt((size_t)344064 * 4);
  float* xws      = (float*)nxt((size_t)344064 * 4);
  uint16_t* xbf   = (uint16_t*)nxt((size_t)344064 * 2);
  uint16_t* h1bf  = (uint16_t*)nxt((size_t)1376256 * 2);    // [448][3072]
  float* yws      = (float*)nxt((size_t)344064 * 4);

  // conversions
  k_cast8<<<dim3(32768), dim3(256), 0, stream>>>((const float4*)kve, (uint4*)Abf);
  k_cast8<<<dim3(168), dim3(256), 0, stream>>>((const float4*)tok, (uint4*)xtokb);
  k_transpose_bf16<<<dim3(24, 32, 1), dim3(256), 0, stream>>>(WK, Wkvt, 1024, 768);
  k_transpose_bf16<<<dim3(24, 32, 1), dim3(256), 0, stream>>>(WV, Wkvt + (size_t)768 * 1024, 1024, 768);
  k_transpose_bf16<<<dim3(24, 24, 14), dim3(256), 0, stream>>>(WQ, WQt, 768, 768);
  k_transpose_bf16<<<dim3(96, 24, 1), dim3(256), 0, stream>>>(W1, W1t, 768, 3072);
  k_transpose_bf16<<<dim3(24, 96, 1), dim3(256), 0, stream>>>(W2, W2t, 3072, 768);
  k_bias_concat<<<dim3(6), dim3(256), 0, stream>>>(bK, bV, biaskv);

  // K|V projection -> head-major K, transposed V
  k_gemm_kv<<<dim3(12, 512), dim3(256), 0, stream>>>(Abf, Wkvt, biaskv, Kh, Vt);

  // Q projection (per-t grouped)
  k_gemm_q<<<dim3(12, 14), dim3(256), 0, stream>>>(xtokb, WQt, bQ, Qws);

  // scores + softmax -> attn_w (f32, second output)
  k_scores<<<dim3(2, 12, 32), dim3(256), 0, stream>>>(Qws, Kh, AW);

  // attn_out = attn_w @ V
  k_attnout<<<dim3(12, 32), dim3(256), 0, stream>>>(AW, Vt, AOws);

  // x = LN(tok + attn_out)
  k_add_ln<<<dim3(448), dim3(256), 0, stream>>>(tok, AOws, g1, be1, xws, xbf);

  // FFN
  k_gemm64<true, false><<<dim3(48, 7), dim3(256), 0, stream>>>(xbf, W1t, b1, (void*)h1bf, 768, 3072);
  k_gemm64<false, true><<<dim3(12, 7), dim3(256), 0, stream>>>(h1bf, W2t, b2, (void*)yws, 3072, 768);

  // out = LN(x + ff)
  k_add_ln<<<dim3(448), dim3(256), 0, stream>>>(xws, yws, g2, be2, outp, (uint16_t*)nullptr);
}